// Round 1
// 206.613 us; speedup vs baseline: 1.0774x; 1.0774x over previous
//
#include <hip/hip_runtime.h>
#include <hip/hip_bf16.h>

// Problem: lstm_20169166422798
// x:(64,512,513) W_ih:(200,513) W_hh:(200,50) b_ih:(200) b_hh:(200)
// W_out:(513,50) b_out:(513)  -> out:(64,512,513) fp32

#define B_SZ 64
#define T_SZ 512
#define F_SZ 513
#define H_SZ 50
#define G_SZ 200            // 4*H
#define M_SZ (B_SZ * T_SZ)  // 32768

typedef __attribute__((ext_vector_type(8))) short short8;   // bf16x8 MFMA frag
typedef __attribute__((ext_vector_type(4))) float f32x4;    // MFMA acc
typedef __attribute__((ext_vector_type(4), aligned(4))) float f32x4u;  // 4B-aligned vec load

__device__ __forceinline__ float bf2f(unsigned short u) {
  unsigned int v = ((unsigned int)u) << 16;
  return __builtin_bit_cast(float, v);
}
__device__ __forceinline__ unsigned short f2bf(float f) {
  unsigned int b = __builtin_bit_cast(unsigned int, f);
  unsigned int r = b + 0x7FFFu + ((b >> 16) & 1u);
  return (unsigned short)(r >> 16);
}

// --------------- K0w: W_ih and W_out -> bf16 MFMA fragments (consumption order)
// Wf_ih[((t*13+nt)*64+lane)] : n=nt*16+(lane&15), k=t*32+(lane>>4)*8+j, t=0..16
// Wf_out[((t*33+nt)*64+lane)]: n=nt*16+(lane&15), k=t*32+(lane>>4)*8+j, t=0..1
#define NF_IH (17 * 13 * 64)
#define NF_OUT (2 * 33 * 64)
__global__ __launch_bounds__(256) void conv_weights(
    const float* __restrict__ Wih, const float* __restrict__ Wout,
    unsigned short* __restrict__ Wf_ih, unsigned short* __restrict__ Wf_out) {
  int idx = blockIdx.x * 256 + threadIdx.x;
  if (idx < NF_IH) {
    int lane = idx & 63;
    int nt = (idx >> 6) % 13;
    int t = idx / (13 * 64);
    int n = nt * 16 + (lane & 15);
    int k0 = t * 32 + (lane >> 4) * 8;
    short8 v;
#pragma unroll
    for (int j = 0; j < 8; j++) {
      int k = k0 + j;
      v[j] = (n < G_SZ && k < F_SZ) ? (short)f2bf(Wih[(size_t)n * F_SZ + k])
                                    : (short)0;
    }
    *(short8*)(Wf_ih + (size_t)idx * 8) = v;
  } else if (idx < NF_IH + NF_OUT) {
    int id2 = idx - NF_IH;
    int lane = id2 & 63;
    int nt = (id2 >> 6) % 33;
    int t = id2 / (33 * 64);
    int n = nt * 16 + (lane & 15);
    int k0 = t * 32 + (lane >> 4) * 8;
    short8 v;
#pragma unroll
    for (int j = 0; j < 8; j++) {
      int k = k0 + j;
      v[j] = (n < F_SZ && k < H_SZ) ? (short)f2bf(Wout[(size_t)n * H_SZ + k])
                                    : (short)0;
    }
    *(short8*)(Wf_out + (size_t)id2 * 8) = v;
  }
}

// ---------------------------------------------------------------- K1: xg GEMM
// xg(32768 x 200, bf16) = x(32768 x 513, fp32, converted in-register) @ W_ih^T
// + b_ih.  x->bf16 conversion FUSED here: each x element is consumed by exactly
// one lane (zero reuse), so the old bf16 staging pass (36MB write + 36MB read +
// a whole kernel) was pure overhead.  A-loads: two 4B-aligned float4 per t.
// mfma(FIRST=Wf, SECOND=x-frag): reg r -> n = nt*16+kg*4+r, lane&15 -> m.
__global__ __launch_bounds__(256) void gemm_xg_mfma(
    const float* __restrict__ x, const unsigned short* __restrict__ Wf,
    const float* __restrict__ bih, unsigned short* __restrict__ xg) {
  int wave = threadIdx.x >> 6;
  int lane = threadIdx.x & 63;
  int m0 = blockIdx.x * 64 + wave * 16;
  int arow = lane & 15;  // m within tile
  int kg = lane >> 4;

  f32x4 acc[13];
#pragma unroll
  for (int nt = 0; nt < 13; nt++) acc[nt] = (f32x4){0.f, 0.f, 0.f, 0.f};

  const float* xr = x + (size_t)(m0 + arow) * F_SZ;  // fp32 row, 4B-aligned
  const short8* Bf = (const short8*)Wf;

#pragma unroll 4
  for (int t = 0; t < 17; t++) {
    short8 af;
    if (t < 16) {
      int k0 = t * 32 + kg * 8;  // k0+7 <= 511 < 513, always in-bounds
      f32x4u lo = *(const f32x4u*)(xr + k0);
      f32x4u hi = *(const f32x4u*)(xr + k0 + 4);
#pragma unroll
      for (int jj = 0; jj < 4; jj++) af[jj] = (short)f2bf(lo[jj]);
#pragma unroll
      for (int jj = 0; jj < 4; jj++) af[4 + jj] = (short)f2bf(hi[jj]);
    } else {
      af = (short8){0, 0, 0, 0, 0, 0, 0, 0};
      if (kg == 0) af[0] = (short)f2bf(xr[512]);  // k=512 real; rest padded
    }
#pragma unroll
    for (int nt = 0; nt < 13; nt++) {
      short8 bf = Bf[(t * 13 + nt) * 64 + lane];
      acc[nt] = __builtin_amdgcn_mfma_f32_16x16x32_bf16(bf, af, acc[nt], 0, 0, 0);
    }
  }

  unsigned short* xrow = xg + (size_t)(m0 + arow) * G_SZ;
#pragma unroll
  for (int nt = 0; nt < 13; nt++) {
    int nb = nt * 16 + kg * 4;
    if (nt < 12 || kg < 2) {  // n < 200
      float4 bi = *(const float4*)&bih[nb];
      ushort4 o;
      o.x = f2bf(acc[nt][0] + bi.x);
      o.y = f2bf(acc[nt][1] + bi.y);
      o.z = f2bf(acc[nt][2] + bi.z);
      o.w = f2bf(acc[nt][3] + bi.w);
      *(ushort4*)(xrow + nb) = o;
    }
  }
}

// ------------------------------------------------------------- K2: recurrence
__device__ __forceinline__ float sig_f(float v) {
  return 1.0f / (1.0f + __expf(-v));
}
__device__ __forceinline__ float tanh_f(float v) {
  return 2.0f / (1.0f + __expf(-2.0f * v)) - 1.0f;
}

// One 256-thread block per t; wave g owns gate g (50 w-VGPRs).
// __launch_bounds__(256,2): grid is 512 blocks = 2 blocks/CU = 2 waves/SIMD max,
// so budget 256 VGPRs -- w[50] + prefetch buffers MUST stay in registers
// (previous build reported VGPR_Count=44, i.e. w[] was spilled/AGPR-parked).
// xg stream: 8-step-deep ping-pong register prefetch (4+4), all static indexing,
// so no per-step exposed HBM latency (old version prefetched only 2 ahead and
// converted immediately -> vmcnt wait inside each step).
// ONE barrier per step: h_s is per-wave private; gact double-buffered by parity.
__global__ __launch_bounds__(256, 2) void lstm_rec(
    const unsigned short* __restrict__ xg, const float* __restrict__ Whh,
    const float* __restrict__ bhh, unsigned short* __restrict__ hs_b) {
  int t = blockIdx.x;
  int g = threadIdx.x >> 6;   // gate 0..3 (i,f,g,o)
  int j = threadIdx.x & 63;
  int jc = (j < H_SZ) ? j : (H_SZ - 1);
  __shared__ __align__(16) float h_s[4][64];     // per-wave private h copy
  __shared__ __align__(16) float gact[2][4][64]; // double-buffered activations

  int grow = g * H_SZ + jc;
  float bh = bhh[grow];
  float w[50];
#pragma unroll
  for (int k = 0; k < 50; k++) w[k] = Whh[(size_t)grow * H_SZ + k];

  h_s[g][j] = 0.f;
  float c = 0.f;

  const size_t bstride = (size_t)T_SZ * G_SZ;
  const unsigned short* xp = xg + (size_t)t * G_SZ + grow;

  // prologue: groups 0 (b=0..3) and 1 (b=4..7) in flight
  unsigned short r0[4], r1[4];
#pragma unroll
  for (int q = 0; q < 4; q++) r0[q] = xp[(size_t)q * bstride];
#pragma unroll
  for (int q = 0; q < 4; q++) r1[q] = xp[(size_t)(4 + q) * bstride];

#pragma unroll 1
  for (int b0 = 0; b0 < B_SZ; b0 += 8) {
    float f0[4], f1[4];
    // consume group b0 (loads issued 8 steps ago -> latency hidden), refill
#pragma unroll
    for (int q = 0; q < 4; q++) f0[q] = bf2f(r0[q]);
    if (b0 + 8 < B_SZ) {
#pragma unroll
      for (int q = 0; q < 4; q++) r0[q] = xp[(size_t)(b0 + 8 + q) * bstride];
    }
#pragma unroll
    for (int q = 0; q < 4; q++) f1[q] = bf2f(r1[q]);
    if (b0 + 12 < B_SZ) {
#pragma unroll
      for (int q = 0; q < 4; q++) r1[q] = xp[(size_t)(b0 + 12 + q) * bstride];
    }

#pragma unroll
    for (int u = 0; u < 8; u++) {  // static u: f0/f1 and gact parity fold
      float a0 = ((u < 4) ? f0[u] : f1[u - 4]) + bh;
      float a1 = 0.f, a2 = 0.f, a3 = 0.f;

      const float4* h4 = (const float4*)h_s[g];
#pragma unroll
      for (int kq = 0; kq < 12; kq++) {
        float4 hv = h4[kq];
        a0 = fmaf(hv.x, w[4 * kq + 0], a0);
        a1 = fmaf(hv.y, w[4 * kq + 1], a1);
        a2 = fmaf(hv.z, w[4 * kq + 2], a2);
        a3 = fmaf(hv.w, w[4 * kq + 3], a3);
      }
      float2 ht = *(const float2*)(h_s[g] + 48);
      a0 = fmaf(ht.x, w[48], a0);
      a1 = fmaf(ht.y, w[49], a1);
      float av = (a0 + a2) + (a1 + a3);

      gact[u & 1][g][j] = (g == 2) ? tanh_f(av) : sig_f(av);
      __syncthreads();  // the only barrier per step

      float iv = gact[u & 1][0][jc];
      float fv = gact[u & 1][1][jc];
      float gv = gact[u & 1][2][jc];
      float ov = gact[u & 1][3][jc];
      c = fmaf(fv, c, iv * gv);
      float h = ov * tanh_f(c);

      h_s[g][j] = (j < H_SZ) ? h : 0.f;  // own copy; in-wave ordering only
      if (g == 1) {
        int b = b0 + u;
        hs_b[((size_t)b * T_SZ + t) * 64 + j] = f2bf((j < H_SZ) ? h : 0.f);
      }
    }
  }
}

// ------------------------------------------------------------ K3: out GEMM
// out(32768 x 513, fp32) = hs_b(32768 x 64, bf16, k-padded) @ Wout^T + b_out.
// mfma(FIRST=Wf_out, SECOND=hs-frag): reg r -> f = nt*16+kg*4+r, lane&15 -> m
// => one float4 store of 4 consecutive f per nt (dense, write-bound).
__global__ __launch_bounds__(256) void gemm_out_mfma(
    const unsigned short* __restrict__ hs_b,
    const unsigned short* __restrict__ Wf, const float* __restrict__ bout,
    float* __restrict__ out) {
  int wave = threadIdx.x >> 6;
  int lane = threadIdx.x & 63;
  int m0 = blockIdx.x * 64 + wave * 16;
  int arow = lane & 15;  // m within tile
  int kg = lane >> 4;

  const short8* Af = (const short8*)(hs_b + (size_t)(m0 + arow) * 64);
  short8 af0 = Af[kg];      // k = kg*8
  short8 af1 = Af[4 + kg];  // k = 32 + kg*8
  const short8* Bf = (const short8*)Wf;
  float* orow = out + (size_t)(m0 + arow) * F_SZ;

#pragma unroll 4
  for (int nt = 0; nt < 32; nt++) {
    short8 bf0 = Bf[nt * 64 + lane];
    short8 bf1 = Bf[(33 + nt) * 64 + lane];
    f32x4 acc = (f32x4){0.f, 0.f, 0.f, 0.f};
    acc = __builtin_amdgcn_mfma_f32_16x16x32_bf16(bf0, af0, acc, 0, 0, 0);
    acc = __builtin_amdgcn_mfma_f32_16x16x32_bf16(bf1, af1, acc, 0, 0, 0);
    int f0 = nt * 16 + kg * 4;
    float4 bv = *(const float4*)&bout[f0];
    float4 o = make_float4(acc[0] + bv.x, acc[1] + bv.y, acc[2] + bv.z,
                           acc[3] + bv.w);
    *(float4*)(orow + f0) = o;  // rows 4B-aligned; HW handles unaligned x4
  }
  // nt = 32: only f = 512 is real
  {
    short8 bf0 = Bf[32 * 64 + lane];
    short8 bf1 = Bf[(33 + 32) * 64 + lane];
    f32x4 acc = (f32x4){0.f, 0.f, 0.f, 0.f};
    acc = __builtin_amdgcn_mfma_f32_16x16x32_bf16(bf0, af0, acc, 0, 0, 0);
    acc = __builtin_amdgcn_mfma_f32_16x16x32_bf16(bf1, af1, acc, 0, 0, 0);
    if (kg == 0) orow[512] = acc[0] + bout[512];
  }
}

extern "C" void kernel_launch(void* const* d_in, const int* in_sizes, int n_in,
                              void* d_out, int out_size, void* d_ws,
                              size_t ws_size, hipStream_t stream) {
  const float* x = (const float*)d_in[0];
  const float* Wih = (const float*)d_in[1];
  const float* Whh = (const float*)d_in[2];
  const float* bih = (const float*)d_in[3];
  const float* bhh = (const float*)d_in[4];
  const float* Wout = (const float*)d_in[5];
  const float* bout = (const float*)d_in[6];
  float* out = (float*)d_out;

  // ws layout (17.6 MB):
  //   xg_b   : bf16 [32768][200]   13,107,200 B @ 0
  //   hs_b   : bf16 [32768][64]     4,194,304 B @ 13,107,200
  //   Wf_ih  : 17*13*64 frags         226,304 B @ 17,301,504
  //   Wf_out : 2*33*64 frags           67,584 B @ 17,527,808
  // (x->bf16 staging pass removed: conversion fused into gemm_xg_mfma)
  unsigned short* xg_b = (unsigned short*)d_ws;
  unsigned short* hs_b = (unsigned short*)((char*)d_ws + 13107200);
  unsigned short* Wf_ih = (unsigned short*)((char*)d_ws + 17301504);
  unsigned short* Wf_out = (unsigned short*)((char*)d_ws + 17527808);

  conv_weights<<<(NF_IH + NF_OUT + 255) / 256, 256, 0, stream>>>(Wih, Wout,
                                                                 Wf_ih, Wf_out);

  gemm_xg_mfma<<<M_SZ / 64, 256, 0, stream>>>(x, Wf_ih, bih, xg_b);

  lstm_rec<<<T_SZ, 256, 0, stream>>>(xg_b, Whh, bhh, hs_b);

  gemm_out_mfma<<<M_SZ / 64, 256, 0, stream>>>(hs_b, Wf_out, bout, out);
}